// Round 5
// baseline (1990.658 us; speedup 1.0000x reference)
//
#include <hip/hip_runtime.h>

#define HIDDEN  64
#define T_STEPS 2048
#define N_INPUT 5
#define DT      0.1f
#define LN_EPS  1e-5f
#define ROWS    16                     // batch rows per block (MFMA N)
#define TANH_K  2.885390081777927f     // 2*log2(e)  (tanh(y) via e=2^(K*y))

typedef short bf16x8 __attribute__((ext_vector_type(8)));
typedef float f32x4  __attribute__((ext_vector_type(4)));

union FragU { uint4 u4; unsigned int u[4]; unsigned short us[8]; bf16x8 v; };

__device__ __forceinline__ unsigned short bf16_trunc(float f) {
    return (unsigned short)(__float_as_uint(f) >> 16);
}
__device__ __forceinline__ float bf16_hi_f32(float f) {
    return __uint_as_float(__float_as_uint(f) & 0xFFFF0000u);
}
// pack bf16-trunc(f0) into low half, bf16-trunc(f1) into high half: one v_perm_b32
__device__ __forceinline__ unsigned int bf16_pack2(float f0, float f1) {
    return __builtin_amdgcn_perm(__float_as_uint(f1), __float_as_uint(f0), 0x07060302u);
}
template <int XMASK>
__device__ __forceinline__ float swz_xor(float v) {   // xor within 32-lane halves
    return __uint_as_float(
        __builtin_amdgcn_ds_swizzle(__float_as_uint(v), (XMASK << 10) | 0x1F));
}
__device__ __forceinline__ float bperm(int addr32, float v) {  // lane^32 exchange
    return __uint_as_float(__builtin_amdgcn_ds_bpermute(addr32, __float_as_uint(v)));
}

#define MFMA(A, B, C) __builtin_amdgcn_mfma_f32_16x16x32_bf16((A), (B), (C), 0, 0, 0)

// build hi/lo bf16 B-frags for the x projection; only q==0 lanes carry data
__device__ __forceinline__ void pack_bx(const float xf[N_INPUT], unsigned int qmask,
                                        FragU& hi, FragU& lo) {
    float z[N_INPUT], l[N_INPUT];
#pragma unroll
    for (int s = 0; s < N_INPUT; ++s) {
        z[s] = __uint_as_float(__float_as_uint(xf[s]) & qmask);
        l[s] = z[s] - bf16_hi_f32(z[s]);
    }
    hi.u[0] = bf16_pack2(z[0], z[1]); hi.u[1] = bf16_pack2(z[2], z[3]);
    hi.u[2] = bf16_pack2(z[4], 0.f);  hi.u[3] = 0u;
    lo.u[0] = bf16_pack2(l[0], l[1]); lo.u[1] = bf16_pack2(l[2], l[3]);
    lo.u[2] = bf16_pack2(l[4], 0.f);  lo.u[3] = 0u;
}

__global__ __launch_bounds__(256, 1) void hlnn_mfma(
    const float* __restrict__ x, const float* __restrict__ W_in,
    const float* __restrict__ b_in, const float* __restrict__ tau_param,
    const float* __restrict__ W_rec, const float* __restrict__ ln1_w,
    const float* __restrict__ ln1_b, const float* __restrict__ ln2_w,
    const float* __restrict__ ln2_b, const float* __restrict__ head_W,
    const float* __restrict__ head_b, float* __restrict__ out, int Btot)
{
    const int tid  = threadIdx.x;
    const int lane = tid & 63;
    const int w    = tid >> 6;        // wave id = hidden 16-col tile
    const int r    = lane & 15;       // batch row within group (MFMA n / A m)
    const int q    = lane >> 4;       // quad
    const int g    = blockIdx.x;      // 16-row group
    const int addr32 = ((lane ^ 32) & 63) << 2;
    const unsigned int qmask = (q == 0) ? 0xFFFFFFFFu : 0u;

    // h transposed transport: [row][hidden] bf16, 72-ushort (144B) row stride
    __shared__ unsigned short hHi[ROWS][72];
    __shared__ unsigned short hLo[ROWS][72];
    __shared__ float stats[ROWS][12];          // [row][wave*2 + {sum,sq}]
    __shared__ float hnbuf[ROWS][68];          // epilogue LN2 output

    // ---- static A fragments: A[m=lane&15][k=q*8+j] = W_rec[k][16w+m], split hi/lo
    FragU A_hi[2], A_lo[2];
    const int cfrag = 16 * w + r;              // global hidden col of this lane's A
#pragma unroll
    for (int kk = 0; kk < 2; ++kk)
#pragma unroll
        for (int j = 0; j < 8; ++j) {
            const float wv = W_rec[(kk * 32 + q * 8 + j) * HIDDEN + cfrag];
            A_hi[kk].us[j] = bf16_trunc(wv);
            A_lo[kk].us[j] = bf16_trunc(wv - bf16_hi_f32(wv));
        }
    FragU Ax_hi, Ax_lo;                        // W_in^T, K=32 (rows >=5 zero)
#pragma unroll
    for (int j = 0; j < 8; ++j) {
        const int kg = q * 8 + j;
        const float wv = (kg < N_INPUT) ? W_in[kg * HIDDEN + cfrag] : 0.0f;
        Ax_hi.us[j] = bf16_trunc(wv);
        Ax_lo.us[j] = bf16_trunc(wv - bf16_hi_f32(wv));
    }

    // ---- per-lane elementwise constants: this lane owns (c = 16w+4q+e, row r)
    float l1wK[4], l1bK[4], dec4[4];
    f32x4 cinit;
#pragma unroll
    for (int e = 0; e < 4; ++e) {
        const int c = 16 * w + 4 * q + e;
        l1wK[e]  = ln1_w[c] * TANH_K;          // fold tanh arg scale into LN
        l1bK[e]  = ln1_b[c] * TANH_K;
        const float tp  = tau_param[c];
        const float tau = (tp > 20.0f) ? tp : log1pf(expf(tp));   // softplus
        dec4[e]  = 1.0f - DT / tau;
        cinit[e] = b_in[c];                                       // MFMA C-init
    }

    const float* xrow = x + (size_t)(g * ROWS + r) * T_STEPS * N_INPUT;

    // ---- x pipeline: Bx[t&1] consumed at t; packed at t for t+2 from xb[t&1];
    //      xb[t&1] loaded at t with x_{t+4}.
    FragU BxHi[2], BxLo[2];
    float xb[2][5];
    {
        float x0[N_INPUT], x1[N_INPUT];
#pragma unroll
        for (int s = 0; s < N_INPUT; ++s) { x0[s] = xrow[s]; x1[s] = xrow[N_INPUT + s]; }
        pack_bx(x0, qmask, BxHi[0], BxLo[0]);
        pack_bx(x1, qmask, BxHi[1], BxLo[1]);
#pragma unroll
        for (int s = 0; s < N_INPUT; ++s) {
            xb[0][s] = xrow[2 * N_INPUT + s];
            xb[1][s] = xrow[3 * N_INPUT + s];
        }
    }

    // h_0 = 0: prime LDS so the loop can read unconditionally
    {
        const int c0 = 16 * w + 4 * q;
        *(uint2*)&hHi[r][c0] = make_uint2(0u, 0u);
        *(uint2*)&hLo[r][c0] = make_uint2(0u, 0u);
    }
    __syncthreads();

    float h[4] = {0.f, 0.f, 0.f, 0.f};         // fp32 state: (c=16w+4q+e, row r)
    const f32x4 kz = {0.f, 0.f, 0.f, 0.f};

#pragma unroll 2
    for (int t = 0; t < T_STEPS; ++t) {
        const int pb = t & 1;

        // B-frags of h_t (written before last barrier)
        FragU Bh[2], Bl[2];
#pragma unroll
        for (int kk = 0; kk < 2; ++kk) {
            Bh[kk].u4 = *(const uint4*)&hHi[r][kk * 32 + q * 8];
            Bl[kk].u4 = *(const uint4*)&hLo[r][kk * 32 + q * 8];
        }

        // 4 independent MFMA chains: x-chain (depth 3) feeds accA; accB/accC depth 2
        f32x4 accA = MFMA(Ax_hi.v, BxHi[pb].v, cinit);
        accA = MFMA(Ax_lo.v, BxHi[pb].v, accA);
        accA = MFMA(Ax_hi.v, BxLo[pb].v, accA);
        accA = MFMA(A_hi[0].v, Bh[0].v, accA);
        accA = MFMA(A_hi[1].v, Bh[1].v, accA);
        f32x4 accB = MFMA(A_lo[0].v, Bh[0].v, kz);
        accB = MFMA(A_lo[1].v, Bh[1].v, accB);
        f32x4 accC = MFMA(A_hi[0].v, Bl[0].v, kz);
        accC = MFMA(A_hi[1].v, Bl[1].v, accC);

        f32x4 acc;
#pragma unroll
        for (int e = 0; e < 4; ++e) acc[e] = accA[e] + (accB[e] + accC[e]);

        // LN stats: lane's 4 values all belong to row r -> local + q-reduce
        float s1 = (acc[0] + acc[1]) + (acc[2] + acc[3]);
        float s2 = fmaf(acc[0], acc[0], fmaf(acc[1], acc[1],
                   fmaf(acc[2], acc[2], acc[3] * acc[3])));
        s1 += swz_xor<16>(s1);  s2 += swz_xor<16>(s2);
        s1 += bperm(addr32, s1); s2 += bperm(addr32, s2);
        if (q == 0) *(float2*)&stats[r][2 * w] = make_float2(s1, s2);

        // fill the pre-barrier slot with independent x-pipeline work:
        // pack Bx for t+2 from xb (x_{t+2}); issue loads of x_{t+4} into xb
        pack_bx(xb[pb], qmask, BxHi[pb], BxLo[pb]);
        {
            const size_t toff = (size_t)((t + 4 < T_STEPS) ? (t + 4) : (T_STEPS - 1)) * N_INPUT;
#pragma unroll
            for (int s = 0; s < N_INPUT; ++s) xb[pb][s] = xrow[toff + s];
        }
        __syncthreads();                       // barrier 1: stats visible

        const float4 sa = *(const float4*)&stats[r][0];
        const float4 sb = *(const float4*)&stats[r][4];
        const float sum = (sa.x + sa.z) + (sb.x + sb.z);
        const float ssq = (sa.y + sa.w) + (sb.y + sb.w);

        const float mu   = sum * (1.0f / 64.0f);
        float var        = fmaf(mu, -mu, ssq * (1.0f / 64.0f));
        var              = fmaxf(var, 0.0f);
        const float rstd = __builtin_amdgcn_rsqf(var + LN_EPS);

        // y2 = K*LN(pre); f = tanh = 1 - 2*rcp(e+1); h' = clip(dec*h + DT*f)
#pragma unroll
        for (int e = 0; e < 4; ++e) {
            const float a1 = rstd * l1wK[e];
            const float a0 = fmaf(-mu, a1, l1bK[e]);
            float y2 = fmaf(acc[e], a1, a0);
            y2 = fminf(fmaxf(y2, -43.3f), 43.3f);
            const float ex = exp2f(y2);
            const float rc = __builtin_amdgcn_rcpf(ex + 1.0f);
            float hv = fmaf(dec4[e], h[e], DT);        // dec*h + DT*1
            hv = fmaf(-2.0f * DT, rc, hv);             // - DT*2*rc  => dec*h + DT*tanh
            h[e] = fminf(fmaxf(hv, -10.0f), 10.0f);
        }

        // split h -> bf16 hi/lo, write transposed to LDS
        {
            const int c0 = 16 * w + 4 * q;
            const float l0 = h[0] - bf16_hi_f32(h[0]), l1v = h[1] - bf16_hi_f32(h[1]);
            const float l2 = h[2] - bf16_hi_f32(h[2]), l3v = h[3] - bf16_hi_f32(h[3]);
            *(uint2*)&hHi[r][c0] = make_uint2(bf16_pack2(h[0], h[1]), bf16_pack2(h[2], h[3]));
            *(uint2*)&hLo[r][c0] = make_uint2(bf16_pack2(l0, l1v), bf16_pack2(l2, l3v));
        }
        __syncthreads();                       // barrier 2: h_{t+1} visible
    }

    // ---- epilogue: LN2 on final h, then 5x4 heads ----
    {
        float s1 = (h[0] + h[1]) + (h[2] + h[3]);
        float s2 = fmaf(h[0], h[0], fmaf(h[1], h[1], fmaf(h[2], h[2], h[3] * h[3])));
        s1 += swz_xor<16>(s1);  s2 += swz_xor<16>(s2);
        s1 += bperm(addr32, s1); s2 += bperm(addr32, s2);
        if (q == 0) *(float2*)&stats[r][2 * w] = make_float2(s1, s2);
        __syncthreads();
        const float4 sa = *(const float4*)&stats[r][0];
        const float4 sb = *(const float4*)&stats[r][4];
        const float sum = (sa.x + sa.z) + (sb.x + sb.z);
        const float ssq = (sa.y + sa.w) + (sb.y + sb.w);
        const float mu   = sum * (1.0f / 64.0f);
        float var        = fmaf(mu, -mu, ssq * (1.0f / 64.0f));
        var              = fmaxf(var, 0.0f);
        const float rstd = __builtin_amdgcn_rsqf(var + LN_EPS);
        const int c0 = 16 * w + 4 * q;
        float hn[4];
#pragma unroll
        for (int e = 0; e < 4; ++e)
            hn[e] = fmaf((h[e] - mu) * rstd, ln2_w[c0 + e], ln2_b[c0 + e]);
        *(float4*)&hnbuf[r][c0] = make_float4(hn[0], hn[1], hn[2], hn[3]);
    }
    __syncthreads();

    for (int o = tid; o < ROWS * 20; o += 256) {
        const int rr = o / 20, ka = o % 20;
        float p = head_b[ka];
#pragma unroll
        for (int c = 0; c < HIDDEN; ++c)
            p = fmaf(hnbuf[rr][c], head_W[ka * HIDDEN + c], p);
        const int k = ka >> 2, a = ka & 3;     // out[k][b][a], shape (5,B,4)
        out[(size_t)k * Btot * 4 + (size_t)(g * ROWS + rr) * 4 + a] = p;
    }
}

extern "C" void kernel_launch(void* const* d_in, const int* in_sizes, int n_in,
                              void* d_out, int out_size, void* d_ws, size_t ws_size,
                              hipStream_t stream) {
    const float* x         = (const float*)d_in[0];
    const float* W_in      = (const float*)d_in[1];
    const float* b_in      = (const float*)d_in[2];
    const float* tau_param = (const float*)d_in[3];
    const float* W_rec     = (const float*)d_in[4];
    const float* ln1_w     = (const float*)d_in[5];
    const float* ln1_b     = (const float*)d_in[6];
    const float* ln2_w     = (const float*)d_in[7];
    const float* ln2_b     = (const float*)d_in[8];
    const float* head_W    = (const float*)d_in[9];
    const float* head_b    = (const float*)d_in[10];

    const int B = in_sizes[0] / (T_STEPS * N_INPUT);   // 4096
    dim3 grid(B / ROWS), block(256);                   // 256 blocks x 4 waves
    hipLaunchKernelGGL(hlnn_mfma, grid, block, 0, stream,
                       x, W_in, b_in, tau_param, W_rec, ln1_w, ln1_b,
                       ln2_w, ln2_b, head_W, head_b, (float*)d_out, B);
}